// Round 7
// baseline (1212.317 us; speedup 1.0000x reference)
//
#include <hip/hip_runtime.h>
#include <hip/hip_bf16.h>
#include <stdint.h>

#define B_ 64
#define T_ 128
#define E_ 256
#define H_ 1024
#define G_ 4096   // 4*H
#define V_ 32000
#define HS_ 65536 // elements per h buffer (64 rows x 1024 cols, bf16)

typedef __attribute__((ext_vector_type(8))) short short8;
typedef __attribute__((ext_vector_type(4))) float floatx4;

static __device__ __forceinline__ unsigned short f2bf(float f){
  union { float f; unsigned u; } v; v.f = f;
  unsigned r = v.u + 0x7FFFu + ((v.u >> 16) & 1u);  // RNE
  return (unsigned short)(r >> 16);
}
static __device__ __forceinline__ float bf2f(unsigned short s){
  union { unsigned u; float f; } v; v.u = ((unsigned)s) << 16;
  return v.f;
}
static __device__ __forceinline__ float sigmoidf_(float x){
  return 1.0f / (1.0f + __expf(-x));
}
static __device__ __forceinline__ float tanhf_(float x){
  const float a = fabsf(x);
  const float t = 1.0f - 2.0f / (__expf(2.0f * a) + 1.0f);
  return __builtin_copysignf(t, x);
}

// ---------------- transpose + bf16-convert the fused LSTM kernel ----------------
__global__ __launch_bounds__(256) void k_transpose(const float* __restrict__ kern,
    unsigned short* __restrict__ wx_t, unsigned short* __restrict__ wh_t){
  __shared__ float tile[32][36];
  const int k0 = blockIdx.x * 32, g0 = blockIdx.y * 32;
  const int r  = threadIdx.x >> 3;
  const int c4 = (threadIdx.x & 7) << 2;
  const float4 v = *reinterpret_cast<const float4*>(kern + (size_t)(k0 + r) * G_ + g0 + c4);
  tile[r][c4 + 0] = v.x; tile[r][c4 + 1] = v.y;
  tile[r][c4 + 2] = v.z; tile[r][c4 + 3] = v.w;
  __syncthreads();
  const unsigned short o0 = f2bf(tile[c4 + 0][r]);
  const unsigned short o1 = f2bf(tile[c4 + 1][r]);
  const unsigned short o2 = f2bf(tile[c4 + 2][r]);
  const unsigned short o3 = f2bf(tile[c4 + 3][r]);
  const ushort4 pk = make_ushort4(o0, o1, o2, o3);
  if (k0 < E_)
    *reinterpret_cast<ushort4*>(wx_t + (size_t)(g0 + r) * E_ + (k0 + c4)) = pk;
  else
    *reinterpret_cast<ushort4*>(wh_t + (size_t)(g0 + r) * H_ + (k0 - E_ + c4)) = pk;
}

// ---------------- xgates, PERMUTED for the LSTM ----------------
// xgp element ((t*256 + wgd)*256 + p)*4 + reg  (bf16), where wgd = hcol>>2
// (0..255) and p = rowblk*64 + quad*16 + gate*4 + c encodes batch-row
// rowblk*16 + quad*4 + reg and gate-col gate*1024 + wgd*4 + c.  (Unchanged
// from R1; the R7 consumer just computes wgd and p from its 2D coords.)
__global__ __launch_bounds__(256) void k_xgates(const float* __restrict__ x,
    const unsigned short* __restrict__ wx_t, const float* __restrict__ bias,
    unsigned short* __restrict__ xgp){
  const int w = threadIdx.x >> 6, l = threadIdx.x & 63;
  const int quad = l >> 4, n = l & 15;
  const int Mbase = blockIdx.x * 64 + w * 16;
  const int Nbase = blockIdx.y * 256;
  const int r = Mbase + n;              // row = t*64 + b
  const int b = r & 63, t = r >> 6;
  const float* arow = x + ((size_t)b * T_ + t) * E_;
  floatx4 acc[16];
  #pragma unroll
  for (int i = 0; i < 16; ++i) acc[i] = (floatx4){0.f,0.f,0.f,0.f};
  #pragma unroll
  for (int kt = 0; kt < 8; ++kt){
    const int k0 = kt * 32 + quad * 8;
    const float4 f0 = *reinterpret_cast<const float4*>(arow + k0);
    const float4 f1 = *reinterpret_cast<const float4*>(arow + k0 + 4);
    short8 af;
    af[0] = (short)f2bf(f0.x); af[1] = (short)f2bf(f0.y);
    af[2] = (short)f2bf(f0.z); af[3] = (short)f2bf(f0.w);
    af[4] = (short)f2bf(f1.x); af[5] = (short)f2bf(f1.y);
    af[6] = (short)f2bf(f1.z); af[7] = (short)f2bf(f1.w);
    const unsigned short* bp = wx_t + (size_t)(Nbase + n) * E_ + k0;
    #pragma unroll
    for (int nt = 0; nt < 16; ++nt){
      const short8 bf = *reinterpret_cast<const short8*>(bp + (size_t)nt * 16 * E_);
      acc[nt] = __builtin_amdgcn_mfma_f32_16x16x32_bf16(af, bf, acc[nt], 0, 0, 0);
    }
  }
  const int t_out = blockIdx.x;
  const int gate = blockIdx.y >> 2;                   // g>>10
  const int np = gate * 4 + (n & 3);                  // gate*4 + c
  #pragma unroll
  for (int nt = 0; nt < 16; ++nt){
    const int g = Nbase + nt * 16 + n;
    const float bi = bias[g];
    const int wgd = (blockIdx.y & 3) * 64 + nt * 4 + (n >> 2);   // (g&1023)>>2
    ushort4 pk;
    pk.x = f2bf(acc[nt][0] + bi);
    pk.y = f2bf(acc[nt][1] + bi);
    pk.z = f2bf(acc[nt][2] + bi);
    pk.w = f2bf(acc[nt][3] + bi);
    *reinterpret_cast<ushort4*>(xgp +
        (((size_t)t_out * 256 + wgd) * 256 + w * 64 + quad * 16 + np) * 4) = pk;
  }
}

// ---------------- persistent LSTM: 2D partition, 4 independent row-groups ----------------
// R7 topology change.  The LSTM recurrence is ROW-INDEPENDENT:
// h_{t+1}[b,:] depends only on h_t[b,:].  So partition WG (r, c):
//   r = wg>>6  owns batch-rows [16r, 16r+16)   (4 row groups)
//   c = wg&63  owns h-cols    [16c, 16c+16)    (4 waves x 4 h-cols)
// Consequences vs R1's flat layout:
//   - the grid barrier splits into 4 INDEPENDENT 64-participant barriers
//     (group r only syncs WGs with the same r): arrival RMWs 4/line,
//     straggler max-of-64 not max-of-256, groups decoupled (jitter in one
//     group no longer stalls the others);
//   - per-WG h-read drops 4x (32 KB: only its 16 rows; all 4 waves read the
//     SAME rows -> L1-resident after the first wave), aggregate 8 MB/step;
//   - per-wave code is BYTE-IDENTICAL to R1 (32 A-loads, 128 weight AGPRs,
//     32 MFMAs, same shuffles/pointwise) -- only address constants differ.
//     VGPR_Count=148 is the canary that codegen held.
// Barrier per group r (R1's proven master/release, participants=64):
//   arrival  bar[r*1024 + (c&15)*32]   (16 lines, 4 RMW/line)
//   release  bar[r*1024 + 512 + i*32]  (16 lines, <=4 pollers/line)
__global__ __launch_bounds__(256, 1) void k_lstm(const unsigned short* __restrict__ wh_t,
    const unsigned short* __restrict__ xgp, unsigned short* __restrict__ hb,
    float* __restrict__ hT, unsigned int* __restrict__ bar){
  const int tid = threadIdx.x;
  const int wg = blockIdx.x;
  const int rg = wg >> 6;                   // row group: batch rows [16rg,16rg+16)
  const int cg = wg & 63;                   // col group: h-cols [16cg,16cg+16)
  const int gbase = rg * 1024;              // this group's barrier region (words)
  const int w = tid >> 6, l = tid & 63, quad = l >> 4, n = l & 15;
  const int hbase = cg * 16 + w * 4;        // this wave's 4 h-cols
  const int g_lane = (n >> 2) * H_ + hbase + (n & 3);
  const int rowb = rg * 16 + quad * 4;
  const bool low8  = (n & 8) == 0;          // lanes holding (i,j) pairs
  const bool first = (n & 4) == 0;          // first gate of the pair

  short8 bfr[32];
  {
    const unsigned short* bp = wh_t + (size_t)g_lane * H_ + quad * 8;
    #pragma unroll
    for (int kt = 0; kt < 32; ++kt)
      bfr[kt] = *reinterpret_cast<const short8*>(bp + kt * 32);
  }
  #pragma unroll
  for (int kt = 0; kt < 32; ++kt)
    __asm__ volatile("" : "+a"(bfr[kt]));   // park Wh in the AGPR file

  float creg[4] = {0.f, 0.f, 0.f, 0.f};
  // xgp consumer index: hcol-quad wgd = cg*4 + w, position p = rg*64 + quad*16 + n
  const size_t xg_wgd = (size_t)(cg * 4 + w);
  const int xg_p = rg * 64 + quad * 16 + n;
  ushort4 xgv = *reinterpret_cast<const ushort4*>(xgp + (xg_wgd * 256 + xg_p) * 4);

  for (int t = 0; t < T_; ++t){
    // A-fragments: flat burst of 32 x 16B loads of this group's 16 h-rows
    const unsigned short* asrc = hb + (size_t)t * HS_ + (size_t)(rg * 16 + n) * H_ + quad * 8;
    short8 afr[32];
    #pragma unroll
    for (int kt = 0; kt < 32; ++kt)
      afr[kt] = *reinterpret_cast<const short8*>(asrc + kt * 32);
    #pragma unroll
    for (int kt = 0; kt < 32; ++kt)
      __asm__ volatile("" : "+v"(afr[kt]));

    floatx4 a0 = {0.f,0.f,0.f,0.f}, a1 = {0.f,0.f,0.f,0.f};
    floatx4 a2 = {0.f,0.f,0.f,0.f}, a3 = {0.f,0.f,0.f,0.f};
    #pragma unroll
    for (int kt = 0; kt < 32; kt += 4){
      a0 = __builtin_amdgcn_mfma_f32_16x16x32_bf16(afr[kt + 0], bfr[kt + 0], a0, 0, 0, 0);
      a1 = __builtin_amdgcn_mfma_f32_16x16x32_bf16(afr[kt + 1], bfr[kt + 1], a1, 0, 0, 0);
      a2 = __builtin_amdgcn_mfma_f32_16x16x32_bf16(afr[kt + 2], bfr[kt + 2], a2, 0, 0, 0);
      a3 = __builtin_amdgcn_mfma_f32_16x16x32_bf16(afr[kt + 3], bfr[kt + 3], a3, 0, 0, 0);
    }
    floatx4 acc = (a0 + a1) + (a2 + a3);
    acc[0] += bf2f(xgv.x); acc[1] += bf2f(xgv.y);
    acc[2] += bf2f(xgv.z); acc[3] += bf2f(xgv.w);

    // pointwise: lane col n -> gate n>>2, h-offset n&3.  Pair up via shuffles.
    float r1o[4], q1[4], q2[4];
    #pragma unroll
    for (int reg = 0; reg < 4; ++reg){
      const float a_ = acc[reg];
      const float p_ = __shfl_xor(a_, 4);   // swap i<->j and f<->o
      const float x1 = first ? a_ : p_;     // i (low) / f (high)
      const float x2 = first ? p_ : a_;     // j (low) / o (high)
      const float s1 = sigmoidf_(low8 ? x1 : (x1 + 1.0f));   // sig(i) or sig(f+1)
      const float r1 = low8 ? s1 * tanhf_(x2) : s1;          // sig(i)*tanh(j) or sig(f+1)
      const float r2 = low8 ? 0.0f : sigmoidf_(x2);          // sig(o)
      r1o[reg] = r1;
      q1[reg] = __shfl_xor(r1, 8);          // low lanes receive sig(f+1)
      q2[reg] = __shfl_xor(r2, 8);          // low lanes receive sig(o)
    }
    if (n < 4){
      unsigned short* hout = hb + (size_t)(t + 1) * HS_;
      #pragma unroll
      for (int reg = 0; reg < 4; ++reg){
        const float cn = creg[reg] * q1[reg] + r1o[reg];
        creg[reg] = cn;
        const float hv = tanhf_(cn) * q2[reg];
        __hip_atomic_store(&hout[(size_t)(rowb + reg) * H_ + hbase + n], f2bf(hv),
                           __ATOMIC_RELAXED, __HIP_MEMORY_SCOPE_AGENT);
        if (t == T_ - 1) hT[(size_t)(hbase + n) * B_ + rowb + reg] = hv;
      }
    }
    // Group-local master/release barrier (R1 code, participants=64).
    if (t < T_ - 1){
      // prefetch next step's x-gates: its HBM RTT rides the store-ack drain
      // inside the same pre-barrier vmcnt(0) (R5 post-mortem: this is free)
      const ushort4 xgv_n = *reinterpret_cast<const ushort4*>(
          xgp + (((size_t)(t + 1) * 256 + xg_wgd) * 256 + xg_p) * 4);
      __syncthreads();                      // drains h stores (vmcnt 0)
      if (tid == 0){
        const unsigned step = (unsigned)(t + 1);
        __asm__ volatile("" ::: "memory");
        __hip_atomic_fetch_add(&bar[gbase + (cg & 15) * 32], 1u,
                               __ATOMIC_RELAXED, __HIP_MEMORY_SCOPE_AGENT);
        if (cg == 0){
          const unsigned tgt = step * 64u;
          unsigned s;
          do {
            s = 0;
            #pragma unroll
            for (int i = 0; i < 16; ++i)
              s += __hip_atomic_load(&bar[gbase + i * 32],
                                     __ATOMIC_RELAXED, __HIP_MEMORY_SCOPE_AGENT);
          } while (s < tgt);
          #pragma unroll
          for (int i = 0; i < 16; ++i)
            __hip_atomic_store(&bar[gbase + 512 + i * 32], step,
                               __ATOMIC_RELAXED, __HIP_MEMORY_SCOPE_AGENT);
        } else {
          while (__hip_atomic_load(&bar[gbase + 512 + (cg & 15) * 32],
                                   __ATOMIC_RELAXED, __HIP_MEMORY_SCOPE_AGENT) < step) {}
        }
        __asm__ volatile("" ::: "memory");
      }
      __syncthreads();
      xgv = xgv_n;
    }
  }
}

// ---------------- projection: out = h127 @ w_out + b_out, single pass ----------------
// grid 500, block 256: each block 64 v-cols x 64 b-rows, full K=1024, bias fused.
__global__ __launch_bounds__(256) void k_proj(const float* __restrict__ w_out,
    const float* __restrict__ hT, const float* __restrict__ b_out,
    float* __restrict__ out){
  __shared__ float wsh[32 * 68];
  __shared__ float hsh[32 * 68];
  const int tid = threadIdx.x;
  const int vbase = blockIdx.x * 64;
  const int vq = tid & 15, bg = tid >> 4;
  floatx4 acc[4] = {{0,0,0,0},{0,0,0,0},{0,0,0,0},{0,0,0,0}};
  for (int c = 0; c < 32; ++c){
    const int k0 = c * 32;
    __syncthreads();
    #pragma unroll
    for (int i = 0; i < 2; ++i){
      const int flat = tid + i * 256;
      const int row = flat >> 4, c4 = (flat & 15) << 2;
      *reinterpret_cast<float4*>(&wsh[row * 68 + c4]) =
        *reinterpret_cast<const float4*>(w_out + (size_t)(k0 + row) * V_ + vbase + c4);
      *reinterpret_cast<float4*>(&hsh[row * 68 + c4]) =
        *reinterpret_cast<const float4*>(hT + (size_t)(k0 + row) * B_ + c4);
    }
    __syncthreads();
    #pragma unroll 8
    for (int k = 0; k < 32; ++k){
      const floatx4 wv = *reinterpret_cast<const floatx4*>(&wsh[k * 68 + vq * 4]);
      #pragma unroll
      for (int j = 0; j < 4; ++j){
        acc[j] += hsh[k * 68 + bg * 4 + j] * wv;
      }
    }
  }
  const floatx4 bv = *reinterpret_cast<const floatx4*>(b_out + vbase + vq * 4);
  #pragma unroll
  for (int j = 0; j < 4; ++j){
    *reinterpret_cast<floatx4*>(out + (size_t)(bg * 4 + j) * V_ + vbase + vq * 4) = acc[j] + bv;
  }
}

extern "C" void kernel_launch(void* const* d_in, const int* in_sizes, int n_in,
                              void* d_out, int out_size, void* d_ws, size_t ws_size,
                              hipStream_t stream){
  (void)in_sizes; (void)n_in; (void)out_size; (void)ws_size;
  const float* x     = (const float*)d_in[0];
  const float* kern  = (const float*)d_in[1];
  const float* bias  = (const float*)d_in[2];
  const float* w_out = (const float*)d_in[3];
  const float* b_out = (const float*)d_in[4];
  float* out = (float*)d_out;
  char* ws = (char*)d_ws;

  const size_t BAR_OFF = 0;                              // 16 KB barrier state:
                                                         //  group r at [r*4096, (r+1)*4096):
                                                         //   +0     16 arrival lines (128B stride)
                                                         //   +2048  16 release lines (128B stride)
  const size_t HB_OFF  = 16384;                          // 129 h buffers, bf16 [64][1024]
  const size_t HT_OFF  = HB_OFF + (size_t)129 * 131072;  // h127 transposed fp32 [1024][64]
  const size_t WX_OFF  = HT_OFF + 262144;                // Wx^T bf16 [4096][256]
  const size_t WH_OFF  = WX_OFF + 2097152;               // Wh^T bf16 [4096][1024]
  const size_t XG_OFF  = WH_OFF + 8388608;               // xgates bf16 permuted (67 MB)

  unsigned int*   bar  = (unsigned int*)(ws + BAR_OFF);
  unsigned short* hb   = (unsigned short*)(ws + HB_OFF);
  float*          hT   = (float*)(ws + HT_OFF);
  unsigned short* wx_t = (unsigned short*)(ws + WX_OFF);
  unsigned short* wh_t = (unsigned short*)(ws + WH_OFF);
  unsigned short* xgp  = (unsigned short*)(ws + XG_OFF);

  hipMemsetAsync(ws, 0, HB_OFF + 131072, stream);  // zero barriers + h buffer 0
  k_transpose<<<dim3(40, 128), 256, 0, stream>>>(kern, wx_t, wh_t);
  k_xgates<<<dim3(128, 16), 256, 0, stream>>>(x, wx_t, bias, xgp);
  k_lstm<<<dim3(256), 256, 0, stream>>>(wh_t, xgp, hb, hT, bar);
  k_proj<<<dim3(500), 256, 0, stream>>>(w_out, hT, b_out, out);
}